// Round 1
// baseline (5725.990 us; speedup 1.0000x reference)
//
#include <hip/hip_runtime.h>
#include <hip/hip_bf16.h>

#define B 64
#define T 256
#define IN 512
#define H 1024
#define L 6

typedef __bf16 bf16x8 __attribute__((ext_vector_type(8)));
typedef float f32x4 __attribute__((ext_vector_type(4)));

// ---------------------------------------------------------------------------
// Prep: cast x (with [B,T,I]->[T,B,I] transpose), weights, h0 to bf16;
// combine biases to fp32.
// ---------------------------------------------------------------------------
__global__ void prep_kernel(const float* __restrict__ x,
                            const float* __restrict__ h0,
                            const float* __restrict__ wih,
                            const float* __restrict__ whh,
                            const float* __restrict__ bih,
                            const float* __restrict__ bhh,
                            __bf16* __restrict__ xbf,
                            __bf16* __restrict__ wihb,
                            __bf16* __restrict__ whhb,
                            float* __restrict__ bias,
                            __bf16* __restrict__ hbuf0) {
    const size_t N1 = (size_t)B * T * IN;   // x
    const size_t N2 = (size_t)L * H * IN;   // wih
    const size_t N3 = (size_t)L * H * H;    // whh
    const size_t N4 = (size_t)L * H;        // bias
    const size_t N5 = (size_t)L * B * H;    // h0
    const size_t Ntot = N1 + N2 + N3 + N4 + N5;
    size_t idx = blockIdx.x * (size_t)blockDim.x + threadIdx.x;
    size_t stride = (size_t)gridDim.x * blockDim.x;
    for (size_t i = idx; i < Ntot; i += stride) {
        if (i < N1) {
            size_t b = i / ((size_t)T * IN);
            size_t r = i % ((size_t)T * IN);
            size_t t = r / IN, c = r % IN;
            xbf[(t * B + b) * IN + c] = (__bf16)x[i];
        } else if (i < N1 + N2) {
            size_t j = i - N1;
            wihb[j] = (__bf16)wih[j];
        } else if (i < N1 + N2 + N3) {
            size_t j = i - N1 - N2;
            whhb[j] = (__bf16)whh[j];
        } else if (i < N1 + N2 + N3 + N4) {
            size_t j = i - N1 - N2 - N3;
            bias[j] = bih[j] + bhh[j];
        } else {
            size_t j = i - N1 - N2 - N3 - N4;
            hbuf0[j] = (__bf16)h0[j];
        }
    }
}

// ---------------------------------------------------------------------------
// One timestep: for every layer l (independent recurrences):
//   h_new[l,b,g] = leaky( sum_i x[t,b,i]*Wih[l,g,i]
//                       + sum_h h[l,b,h]*Whh[l,g,h] + bias[l,g] )
// Grid: 96 blocks = 6 layers x 16 column tiles (64 cols each).
// Block: 256 threads = 4 waves; wave w owns 16 columns.
// A = [x[t] | h[l]] rows (M=64 batch), K = 1536, staged in LDS per 128-k chunk.
// B = weight rows [g][k] (native B^T layout), read direct (L2-resident).
// ---------------------------------------------------------------------------
__global__ __launch_bounds__(256)
void step_kernel(const __bf16* __restrict__ xbf,   // [T][B][IN]
                 const __bf16* __restrict__ wihb,  // [L][H][IN]
                 const __bf16* __restrict__ whhb,  // [L][H][H]
                 const float*  __restrict__ bias,  // [L][H]
                 const __bf16* __restrict__ hin,   // [L][B][H]
                 __bf16* __restrict__ hout,        // [L][B][H]
                 float* __restrict__ out,          // d_out
                 int t) {
    __shared__ __bf16 Alds[64][136];  // 128 cols + pad to stride 136 (16B-mult)

    const int l    = blockIdx.x >> 4;
    const int gt   = blockIdx.x & 15;
    const int tid  = threadIdx.x;
    const int wave = tid >> 6;
    const int lane = tid & 63;
    const int n0   = gt * 64 + wave * 16;
    const int lrow = lane & 15;
    const int lkg  = lane >> 4;

    f32x4 acc[4] = {{0.f,0.f,0.f,0.f},{0.f,0.f,0.f,0.f},
                    {0.f,0.f,0.f,0.f},{0.f,0.f,0.f,0.f}};

    const int srow = tid & 63;   // staging: each thread owns (row, 32-col seg)
    const int sseg = tid >> 6;
    const int g    = n0 + lrow;

    for (int c = 0; c < 12; ++c) {
        const int k0 = c * 128;
        // ---- stage A[64][128] chunk into LDS (x part for k<512, h after) ---
        const __bf16* src;
        if (k0 < IN) src = xbf + ((size_t)t * B + srow) * IN + (k0 + sseg * 32);
        else         src = hin + ((size_t)l * B + srow) * H + (k0 - IN + sseg * 32);
        #pragma unroll
        for (int j = 0; j < 4; ++j) {
            float4 v = *reinterpret_cast<const float4*>(src + j * 8);
            *reinterpret_cast<float4*>(&Alds[srow][sseg * 32 + j * 8]) = v;
        }
        __syncthreads();
        // ---- 4 k-steps of MFMA on this chunk --------------------------------
        #pragma unroll
        for (int kk = 0; kk < 4; ++kk) {
            const int klocal = kk * 32 + lkg * 8;
            const int kglob  = k0 + klocal;
            const __bf16* bsrc = (kglob < IN)
                ? wihb + ((size_t)l * H + g) * IN + kglob
                : whhb + ((size_t)l * H + g) * H + (kglob - IN);
            bf16x8 bfr = *reinterpret_cast<const bf16x8*>(bsrc);
            #pragma unroll
            for (int mf = 0; mf < 4; ++mf) {
                bf16x8 afr = *reinterpret_cast<const bf16x8*>(
                    &Alds[mf * 16 + lrow][klocal]);
                acc[mf] = __builtin_amdgcn_mfma_f32_16x16x32_bf16(
                    afr, bfr, acc[mf], 0, 0, 0);
            }
        }
        __syncthreads();
    }

    // ---- epilogue: bias + leaky relu; write h (bf16), outputs (fp32) -------
    const float bv = bias[l * H + g];
    #pragma unroll
    for (int mf = 0; mf < 4; ++mf) {
        #pragma unroll
        for (int j = 0; j < 4; ++j) {
            const int b = mf * 16 + lkg * 4 + j;   // C/D: col=lane&15, row=(lane>>4)*4+j
            float v = acc[mf][j] + bv;
            v = (v >= 0.f) ? v : 0.01f * v;
            hout[((size_t)l * B + b) * H + g] = (__bf16)v;
            if (l == L - 1)
                out[((size_t)b * T + t) * H + g] = v;          // out[B,T,H]
            if (t == T - 1)
                out[(size_t)B * T * H + ((size_t)l * B + b) * H + g] = v;  // h_T[L,B,H]
        }
    }
}

// ---------------------------------------------------------------------------
extern "C" void kernel_launch(void* const* d_in, const int* in_sizes, int n_in,
                              void* d_out, int out_size, void* d_ws, size_t ws_size,
                              hipStream_t stream) {
    const float* x   = (const float*)d_in[0];
    const float* h0  = (const float*)d_in[1];
    const float* wih = (const float*)d_in[2];
    const float* whh = (const float*)d_in[3];
    const float* bih = (const float*)d_in[4];
    const float* bhh = (const float*)d_in[5];
    float* out = (float*)d_out;

    char* ws = (char*)d_ws;
    size_t off = 0;
    auto alloc = [&](size_t bytes) {
        void* p = ws + off;
        off = (off + bytes + 255) & ~(size_t)255;
        return p;
    };
    __bf16* xbf   = (__bf16*)alloc((size_t)T * B * IN * 2);   // 16 MB
    __bf16* wihb  = (__bf16*)alloc((size_t)L * H * IN * 2);   // 6 MB
    __bf16* whhb  = (__bf16*)alloc((size_t)L * H * H * 2);    // 12 MB
    float*  bias  = (float*) alloc((size_t)L * H * 4);        // 24 KB
    __bf16* hbuf0 = (__bf16*)alloc((size_t)L * B * H * 2);    // 768 KB
    __bf16* hbuf1 = (__bf16*)alloc((size_t)L * B * H * 2);    // 768 KB

    // prep: one element per thread
    {
        const size_t Ntot = (size_t)B*T*IN + (size_t)L*H*IN + (size_t)L*H*H
                          + (size_t)L*H + (size_t)L*B*H;
        int blocks = (int)((Ntot + 255) / 256);
        prep_kernel<<<blocks, 256, 0, stream>>>(x, h0, wih, whh, bih, bhh,
                                                xbf, wihb, whhb, bias, hbuf0);
    }

    // 256 sequential timesteps
    __bf16* hb[2] = {hbuf0, hbuf1};
    for (int t = 0; t < T; ++t) {
        step_kernel<<<L * 16, 256, 0, stream>>>(
            xbf, wihb, whhb, bias, hb[t & 1], hb[(t + 1) & 1], out, t);
    }
}